// Round 6
// baseline (444.739 us; speedup 1.0000x reference)
//
#include <hip/hip_runtime.h>

#define N_NODES 50000
#define N_EDGES 800000
#define IN_DIM 128
#define OUT_DIM 64

#define GROUP_SHIFT 6                 // 64 rows per group
#define GROUP_ROWS 64
#define N_GROUPS 782                  // ceil(50000/64)
#define SLAB 1216                     // slab capacity per group (mean 1024, +6 sigma)
#define CHUNK2 2048                   // edges per fill block
#define FILL_BLOCKS 391               // 391*2048 >= 800000 (fill role on blocks 0..390)

typedef _Float16 h2 __attribute__((ext_vector_type(2)));
typedef _Float16 h4 __attribute__((ext_vector_type(4)));
typedef _Float16 h8 __attribute__((ext_vector_type(8)));
typedef float    f4 __attribute__((ext_vector_type(4)));

#define LDK 136    // padded fp16 K-stride (multiple of 8 -> 16B-aligned b128 rows)

// ---------------------------------------------------------------------------
// D1 (fused, byte-identical to the proven 124.3us version): blocks [0,391) =
// fill role; blocks [391,1173) = MFMA fp16 GEMM per 64-row group.
// ---------------------------------------------------------------------------
__global__ __launch_bounds__(256) void fused_gemm_fill(const float* __restrict__ x,
                                                       const float* __restrict__ w,
                                                       const int* __restrict__ erow,
                                                       const int* __restrict__ ecol,
                                                       const float* __restrict__ eval,
                                                       _Float16* __restrict__ support,
                                                       int* __restrict__ gcursor,
                                                       int2* __restrict__ bucket) {
    __shared__ char smem[GROUP_ROWS * LDK * 2 + OUT_DIM * LDK * 2];  // 34816 B
    const int tid = threadIdx.x;

    if (blockIdx.x >= FILL_BLOCKS) {
        // ---- GEMM role (blocks 391..1172, group = blockIdx-391) ----
        _Float16* xb = (_Float16*)smem;                          // [64][LDK]
        _Float16* wt = (_Float16*)(smem + GROUP_ROWS * LDK * 2); // [64][LDK], wt[n][k]

        // conflict-free wt staging (register transpose, fp16-pair stores)
        {
            const int n_s = tid >> 2;         // 0..63
            const int kp0 = tid & 3;
            #pragma unroll
            for (int it = 0; it < 16; ++it) {
                int kp = kp0 + (it << 2);     // k-pair index 0..63
                int k  = kp << 1;
                h2 hv = { (_Float16)w[(size_t)k * OUT_DIM + n_s],
                          (_Float16)w[(size_t)(k + 1) * OUT_DIM + n_s] };
                *(h2*)&wt[n_s * LDK + k] = hv;
            }
        }
        const int rowbase = (blockIdx.x - FILL_BLOCKS) * GROUP_ROWS;
        for (int i = tid; i < GROUP_ROWS * (IN_DIM / 4); i += 256) {
            int r  = i >> 5;
            int kq = i & 31;
            int row = rowbase + r;
            float4 v = (row < N_NODES)
                           ? *(const float4*)&x[(size_t)row * IN_DIM + kq * 4]
                           : make_float4(0.f, 0.f, 0.f, 0.f);
            h4 hv = { (_Float16)v.x, (_Float16)v.y, (_Float16)v.z, (_Float16)v.w };
            *(h4*)&xb[r * LDK + kq * 4] = hv;
        }
        __syncthreads();

        const int wave = tid >> 6;
        const int lane = tid & 63;
        const int mrow = lane & 15;
        const int quad = lane >> 4;
        const int m0   = wave * 16;

        f4 acc[4];
        #pragma unroll
        for (int t = 0; t < 4; ++t) acc[t] = (f4){0.f, 0.f, 0.f, 0.f};

        #pragma unroll
        for (int ks = 0; ks < 4; ++ks) {
            int kof = ks * 32 + quad * 8;
            h8 a = *(h8*)&xb[(m0 + mrow) * LDK + kof];
            #pragma unroll
            for (int t = 0; t < 4; ++t) {
                h8 b = *(h8*)&wt[(t * 16 + mrow) * LDK + kof];
                acc[t] = __builtin_amdgcn_mfma_f32_16x16x32_f16(a, b, acc[t], 0, 0, 0);
            }
        }

        #pragma unroll
        for (int t = 0; t < 4; ++t) {
            #pragma unroll
            for (int r = 0; r < 4; ++r) {
                int row = rowbase + m0 + quad * 4 + r;
                if (row < N_NODES)
                    support[(size_t)row * OUT_DIM + t * 16 + mrow] = (_Float16)acc[t][r];
            }
        }
    } else {
        // ---- fill role (blocks 0..390) ----
        int* lcnt  = (int*)smem;
        int* lbase = lcnt + N_GROUPS;
        for (int i = tid; i < N_GROUPS; i += 256) lcnt[i] = 0;
        __syncthreads();
        const int base = blockIdx.x * CHUNK2;
        #pragma unroll 4
        for (int i = 0; i < CHUNK2 / 256; ++i) {
            int e = base + tid + i * 256;
            if (e < N_EDGES) atomicAdd(&lcnt[erow[e] >> GROUP_SHIFT], 1);
        }
        __syncthreads();
        for (int i = tid; i < N_GROUPS; i += 256) {
            int c = lcnt[i];
            lbase[i] = c ? atomicAdd(&gcursor[i], c) : 0;
            lcnt[i]  = 0;
        }
        __syncthreads();
        #pragma unroll 4
        for (int i = 0; i < CHUNK2 / 256; ++i) {
            int e = base + tid + i * 256;
            if (e < N_EDGES) {
                int r = erow[e];
                int g = r >> GROUP_SHIFT;
                int p = atomicAdd(&lcnt[g], 1);
                bucket[(size_t)g * SLAB + lbase[g] + p] =
                    make_int2(((r & (GROUP_ROWS - 1)) << 16) | ecol[e],
                              __float_as_int(eval[e]));
            }
        }
    }
}

// ---------------------------------------------------------------------------
// D2 v2: sort-free edge-parallel accumulate.  One 512-thread block per group
// (8 waves -> 4 blocks/CU, all 782 blocks co-resident).  LDS = 64x64 f32
// accumulator only (16KB).  32 units x 16 lanes; unit walks every-32nd slab
// entry (broadcast bucket read, software-pipelined 1 ahead), gathers the
// 128B support row, and does 4 non-returning ds_add_f32 into accum[row].
// Perfectly balanced in cnt regardless of per-row degree; 2 barriers total.
// ---------------------------------------------------------------------------
__global__ __launch_bounds__(512) void reduce_group(const int* __restrict__ gcursor,
                                                    const int2* __restrict__ bucket,
                                                    const _Float16* __restrict__ support,
                                                    float* __restrict__ out) {
    __shared__ float accum[GROUP_ROWS][OUT_DIM];   // 16384 B
    const int grp = blockIdx.x;
    const int cnt = min(gcursor[grp], SLAB);
    const size_t sb = (size_t)grp * SLAB;
    const int tid = threadIdx.x;

    // zero accumulator: 1024 float4 over 512 threads
    {
        float4* az = (float4*)&accum[0][0];
        const float4 z = make_float4(0.f, 0.f, 0.f, 0.f);
        az[tid] = z;
        az[tid + 512] = z;
    }
    __syncthreads();

    const int u = tid >> 4;          // unit 0..31
    const int g = tid & 15;          // lane's column quad

    int j = u;
    int2 cv = (j < cnt) ? bucket[sb + j] : make_int2(0, 0);
    while (j < cnt) {
        const int jn = j + 32;
        int2 nx = (jn < cnt) ? bucket[sb + jn] : make_int2(0, 0);   // prefetch
        const int   rl = cv.x >> 16;
        const float v  = __int_as_float(cv.y);
        h4 s = *(const h4*)&support[(size_t)(cv.x & 0xFFFF) * OUT_DIM + g * 4];
        float* a = &accum[rl][g * 4];
        atomicAdd(a + 0, v * (float)s[0]);
        atomicAdd(a + 1, v * (float)s[1]);
        atomicAdd(a + 2, v * (float)s[2]);
        atomicAdd(a + 3, v * (float)s[3]);
        cv = nx;
        j = jn;
    }
    __syncthreads();

    // writeout with fused ReLU: 1024 float4 over 512 threads
    #pragma unroll
    for (int i = tid; i < GROUP_ROWS * (OUT_DIM / 4); i += 512) {
        const int lr = i >> 4;
        const int q  = i & 15;
        const int row = grp * GROUP_ROWS + lr;
        if (row < N_NODES) {
            const float* a = &accum[lr][q * 4];
            float4 r;
            r.x = fmaxf(a[0], 0.f);
            r.y = fmaxf(a[1], 0.f);
            r.z = fmaxf(a[2], 0.f);
            r.w = fmaxf(a[3], 0.f);
            *(float4*)&out[(size_t)row * OUT_DIM + q * 4] = r;
        }
    }
}

extern "C" void kernel_launch(void* const* d_in, const int* in_sizes, int n_in,
                              void* d_out, int out_size, void* d_ws, size_t ws_size,
                              hipStream_t stream) {
    const float* x    = (const float*)d_in[0];
    const int*   erow = (const int*)  d_in[1];
    const int*   ecol = (const int*)  d_in[2];
    const float* ev   = (const float*)d_in[3];
    const float* w    = (const float*)d_in[4];
    float* out = (float*)d_out;

    // workspace layout (16B-aligned), total ~14.0 MB
    char* ws = (char*)d_ws;
    _Float16* support = (_Float16*)ws;               //  6,400,000 B
    int*  gcursor = (int*)(ws + 6400000);            //      3,128 B
    int2* bucket  = (int2*)(ws + 6403200);           //  7,607,296 B

    hipMemsetAsync(gcursor, 0, sizeof(int) * N_GROUPS, stream);

    fused_gemm_fill<<<FILL_BLOCKS + N_GROUPS, 256, 0, stream>>>(
        x, w, erow, ecol, ev, support, gcursor, bucket);

    reduce_group<<<N_GROUPS, 512, 0, stream>>>(gcursor, bucket, support, out);
}

// Round 7
// 384.974 us; speedup vs baseline: 1.1552x; 1.1552x over previous
//
#include <hip/hip_runtime.h>
#include <hip/hip_cooperative_groups.h>

namespace cg = cooperative_groups;

#define N_NODES 50000
#define N_EDGES 800000
#define IN_DIM 128
#define OUT_DIM 64

#define GROUP_SHIFT 6                 // 64 rows per group
#define GROUP_ROWS 64
#define N_GROUPS 782                  // ceil(50000/64)
#define SLAB 1216                     // slab capacity per group (mean 1024, +6 sigma)
#define GRID_B 1024                   // coop grid: 4 blocks/CU x 256 CU
#define CHUNK 800                     // edges per chunk
#define NCH 1000                      // 1000*800 == 800000 exactly
#define GEMM_FALLBACK_BASE 1000       // fallback phase-2 grid: fill 0..999, gemm 1000..1781

typedef _Float16 h2 __attribute__((ext_vector_type(2)));
typedef _Float16 h4 __attribute__((ext_vector_type(4)));
typedef _Float16 h8 __attribute__((ext_vector_type(8)));
typedef float    f4 __attribute__((ext_vector_type(4)));

#define LDK 136    // padded fp16 K-stride (multiple of 8 -> 16B-aligned b128 rows)

// ---------------------------------------------------------------------------
// One cooperative kernel: count -> grid.sync -> scan -> grid.sync ->
// fill (deterministic, zero global atomics) -> gemm (proven MFMA code).
// phase==3: cooperative all-in-one.  phase 0/1/2: standalone fallback slices
// (launched only if the cooperative launch is rejected).
// ---------------------------------------------------------------------------
__global__ __launch_bounds__(256, 4) void fused_all(const float* __restrict__ x,
                                                    const float* __restrict__ w,
                                                    const int* __restrict__ erow,
                                                    const int* __restrict__ ecol,
                                                    const float* __restrict__ eval,
                                                    _Float16* __restrict__ support,
                                                    unsigned short* __restrict__ cnt16,
                                                    unsigned short* __restrict__ rbase,
                                                    int* __restrict__ gtot,
                                                    int2* __restrict__ bucket,
                                                    int phase) {
    __shared__ char smem[GROUP_ROWS * LDK * 2 + OUT_DIM * LDK * 2];  // 34816 B
    const int tid = threadIdx.x;
    const int bid = blockIdx.x;
    const bool coop = (phase == 3);

    // ---- phase 0: per-chunk group histogram ----
    if (coop || phase == 0) {
        if (bid < NCH) {
            int* lcnt = (int*)smem;
            for (int i = tid; i < N_GROUPS; i += 256) lcnt[i] = 0;
            __syncthreads();
            const int base = bid * CHUNK;
            for (int i = tid; i < CHUNK; i += 256)
                atomicAdd(&lcnt[erow[base + i] >> GROUP_SHIFT], 1);
            __syncthreads();
            for (int i = tid; i < N_GROUPS; i += 256)
                cnt16[(size_t)bid * N_GROUPS + i] = (unsigned short)lcnt[i];
        }
        if (!coop) return;
        cg::this_grid().sync();
    }

    // ---- phase 1: per-group exclusive scan over the 1000 chunk counts ----
    if (coop || phase == 1) {
        if (bid < N_GROUPS) {
            const int g = bid;
            int s[4];
            int lsum = 0;
            #pragma unroll
            for (int k = 0; k < 4; ++k) {
                int ch = tid * 4 + k;
                s[k] = (ch < NCH) ? (int)cnt16[(size_t)ch * N_GROUPS + g] : 0;
                lsum += s[k];
            }
            const int lane = tid & 63;
            const int wid  = tid >> 6;
            int incl = lsum;
            #pragma unroll
            for (int off = 1; off < 64; off <<= 1) {
                int t = __shfl_up(incl, off, 64);
                if (lane >= off) incl += t;
            }
            int* wsum = (int*)smem;
            if (lane == 63) wsum[wid] = incl;
            __syncthreads();
            int wo = 0;
            #pragma unroll
            for (int wv = 0; wv < 4; ++wv)
                if (wv < wid) wo += wsum[wv];
            int run = wo + incl - lsum;
            #pragma unroll
            for (int k = 0; k < 4; ++k) {
                int ch = tid * 4 + k;
                if (ch < NCH) {
                    rbase[(size_t)ch * N_GROUPS + g] = (unsigned short)run;
                    run += s[k];
                }
            }
            if (tid == 255) gtot[g] = wo + incl;
        }
        if (!coop) return;
        cg::this_grid().sync();
    }

    // ---- phase 2: fill (deterministic scatter) + gemm ----
    const int fill_ch = bid;                                 // coop & fallback: chunks on 0..999
    const int gemm_grp = coop ? bid : bid - GEMM_FALLBACK_BASE;
    const bool do_fill = (fill_ch < NCH);
    const bool do_gemm = coop ? (bid < N_GROUPS)
                              : (bid >= GEMM_FALLBACK_BASE &&
                                 gemm_grp < N_GROUPS);

    if (do_fill) {
        int* lcnt = (int*)smem;
        for (int i = tid; i < N_GROUPS; i += 256) lcnt[i] = 0;
        __syncthreads();
        const unsigned short* rb = &rbase[(size_t)fill_ch * N_GROUPS];
        const int base = fill_ch * CHUNK;
        for (int i = tid; i < CHUNK; i += 256) {
            int e = base + i;
            int r = erow[e];
            int g = r >> GROUP_SHIFT;
            int p = atomicAdd(&lcnt[g], 1);                  // LDS, block-local
            int pos = (int)rb[g] + p;                        // exact, race-free
            if (pos < SLAB)
                bucket[(size_t)g * SLAB + pos] =
                    make_int2(((r & (GROUP_ROWS - 1)) << 16) | ecol[e],
                              __float_as_int(eval[e]));
        }
        __syncthreads();                                     // smem reuse below
    }

    if (do_gemm) {
        _Float16* xb = (_Float16*)smem;                          // [64][LDK]
        _Float16* wt = (_Float16*)(smem + GROUP_ROWS * LDK * 2); // [64][LDK], wt[n][k]

        // conflict-free wt staging (register transpose, fp16-pair stores)
        {
            const int n_s = tid >> 2;         // 0..63
            const int kp0 = tid & 3;
            #pragma unroll
            for (int it = 0; it < 16; ++it) {
                int kp = kp0 + (it << 2);     // k-pair index 0..63
                int k  = kp << 1;
                h2 hv = { (_Float16)w[(size_t)k * OUT_DIM + n_s],
                          (_Float16)w[(size_t)(k + 1) * OUT_DIM + n_s] };
                *(h2*)&wt[n_s * LDK + k] = hv;
            }
        }
        const int rowbase = gemm_grp * GROUP_ROWS;
        for (int i = tid; i < GROUP_ROWS * (IN_DIM / 4); i += 256) {
            int r  = i >> 5;
            int kq = i & 31;
            int row = rowbase + r;
            float4 v = (row < N_NODES)
                           ? *(const float4*)&x[(size_t)row * IN_DIM + kq * 4]
                           : make_float4(0.f, 0.f, 0.f, 0.f);
            h4 hv = { (_Float16)v.x, (_Float16)v.y, (_Float16)v.z, (_Float16)v.w };
            *(h4*)&xb[r * LDK + kq * 4] = hv;
        }
        __syncthreads();

        const int wave = tid >> 6;
        const int lane = tid & 63;
        const int mrow = lane & 15;
        const int quad = lane >> 4;
        const int m0   = wave * 16;

        f4 acc[4];
        #pragma unroll
        for (int t = 0; t < 4; ++t) acc[t] = (f4){0.f, 0.f, 0.f, 0.f};

        #pragma unroll
        for (int ks = 0; ks < 4; ++ks) {
            int kof = ks * 32 + quad * 8;
            h8 a = *(h8*)&xb[(m0 + mrow) * LDK + kof];
            #pragma unroll
            for (int t = 0; t < 4; ++t) {
                h8 b = *(h8*)&wt[(t * 16 + mrow) * LDK + kof];
                acc[t] = __builtin_amdgcn_mfma_f32_16x16x32_f16(a, b, acc[t], 0, 0, 0);
            }
        }

        #pragma unroll
        for (int t = 0; t < 4; ++t) {
            #pragma unroll
            for (int r = 0; r < 4; ++r) {
                int row = rowbase + m0 + quad * 4 + r;
                if (row < N_NODES)
                    support[(size_t)row * OUT_DIM + t * 16 + mrow] = (_Float16)acc[t][r];
            }
        }
    }
}

// ---------------------------------------------------------------------------
// D2: proven R0 counting-sort reduce (1024 threads/group): slab -> LDS +
// histogram; wave-0 scan; in-LDS counting sort; 16-lanes-per-row gather with
// dual accumulators; fused ReLU.
// ---------------------------------------------------------------------------
__global__ __launch_bounds__(1024) void reduce_group(const int* __restrict__ gtot,
                                                     const int2* __restrict__ bucket,
                                                     const _Float16* __restrict__ support,
                                                     float* __restrict__ out) {
    __shared__ int2 ebuf[SLAB];
    __shared__ int2 ebuf2[SLAB];
    __shared__ int  rcnt[GROUP_ROWS];
    __shared__ int  rstart[GROUP_ROWS + 1];
    __shared__ int  rcur[GROUP_ROWS];
    const int grp = blockIdx.x;
    const int cnt = min(gtot[grp], SLAB);
    const size_t sb = (size_t)grp * SLAB;
    const int tid = threadIdx.x;

    if (tid < GROUP_ROWS) rcnt[tid] = 0;
    __syncthreads();
    for (int j = tid; j < cnt; j += 1024) {
        int2 cv = bucket[sb + j];
        ebuf[j] = cv;
        atomicAdd(&rcnt[cv.x >> 16], 1);
    }
    __syncthreads();
    if (tid < GROUP_ROWS) {
        int v = rcnt[tid];
        int s = v;
        #pragma unroll
        for (int off = 1; off < 64; off <<= 1) {
            int t = __shfl_up(s, off, 64);
            if (tid >= off) s += t;
        }
        rstart[tid] = s - v;
        rcur[tid]   = s - v;
        if (tid == 63) rstart[64] = s;
    }
    __syncthreads();
    for (int j = tid; j < cnt; j += 1024) {
        int2 cv = ebuf[j];
        int rl = cv.x >> 16;
        int p  = atomicAdd(&rcur[rl], 1);
        ebuf2[p] = cv;
    }
    __syncthreads();

    const int g  = tid & 15;
    const int lr = tid >> 4;
    const int row = grp * GROUP_ROWS + lr;
    const int jb = rstart[lr];
    const int je = rstart[lr + 1];
    float4 acc0 = make_float4(0.f, 0.f, 0.f, 0.f);
    float4 acc1 = make_float4(0.f, 0.f, 0.f, 0.f);
    int j = jb;
    for (; j + 1 < je; j += 2) {
        int2 cv0 = ebuf2[j];
        int2 cv1 = ebuf2[j + 1];
        float v0 = __int_as_float(cv0.y);
        float v1 = __int_as_float(cv1.y);
        h4 s0 = *(const h4*)&support[(size_t)(cv0.x & 0xFFFF) * OUT_DIM + g * 4];
        h4 s1 = *(const h4*)&support[(size_t)(cv1.x & 0xFFFF) * OUT_DIM + g * 4];
        acc0.x += v0 * (float)s0[0];
        acc0.y += v0 * (float)s0[1];
        acc0.z += v0 * (float)s0[2];
        acc0.w += v0 * (float)s0[3];
        acc1.x += v1 * (float)s1[0];
        acc1.y += v1 * (float)s1[1];
        acc1.z += v1 * (float)s1[2];
        acc1.w += v1 * (float)s1[3];
    }
    if (j < je) {
        int2 cv = ebuf2[j];
        float v = __int_as_float(cv.y);
        h4 sr = *(const h4*)&support[(size_t)(cv.x & 0xFFFF) * OUT_DIM + g * 4];
        acc0.x += v * (float)sr[0];
        acc0.y += v * (float)sr[1];
        acc0.z += v * (float)sr[2];
        acc0.w += v * (float)sr[3];
    }
    if (row < N_NODES) {
        float4 a;
        a.x = fmaxf(acc0.x + acc1.x, 0.f);
        a.y = fmaxf(acc0.y + acc1.y, 0.f);
        a.z = fmaxf(acc0.z + acc1.z, 0.f);
        a.w = fmaxf(acc0.w + acc1.w, 0.f);
        *(float4*)&out[(size_t)row * OUT_DIM + g * 4] = a;
    }
}

extern "C" void kernel_launch(void* const* d_in, const int* in_sizes, int n_in,
                              void* d_out, int out_size, void* d_ws, size_t ws_size,
                              hipStream_t stream) {
    const float* x    = (const float*)d_in[0];
    const int*   erow = (const int*)  d_in[1];
    const int*   ecol = (const int*)  d_in[2];
    const float* ev   = (const float*)d_in[3];
    const float* w    = (const float*)d_in[4];
    float* out = (float*)d_out;

    // workspace layout (16B-aligned), total ~17.1 MB (ws is 256 MiB)
    char* ws = (char*)d_ws;
    _Float16*       support = (_Float16*)ws;                  //  6,400,000 B
    unsigned short* cnt16   = (unsigned short*)(ws + 6400000);//  1,564,000 B (1000*782*2)
    unsigned short* rbase   = (unsigned short*)(ws + 7964000);//  1,564,000 B
    int*            gtot    = (int*)(ws + 9528000);           //      3,128 B
    int2*           bucket  = (int2*)(ws + 9531136);          //  7,607,296 B

    int phase = 3;
    void* args[] = { (void*)&x, (void*)&w, (void*)&erow, (void*)&ecol,
                     (void*)&ev, (void*)&support, (void*)&cnt16, (void*)&rbase,
                     (void*)&gtot, (void*)&bucket, (void*)&phase };
    hipError_t cerr = hipLaunchCooperativeKernel((const void*)fused_all,
                                                 dim3(GRID_B), dim3(256),
                                                 args, 0, stream);
    if (cerr != hipSuccess) {
        // fallback: same kernel, 3 phase-split plain dispatches (R3-style)
        fused_all<<<NCH, 256, 0, stream>>>(x, w, erow, ecol, ev, support,
                                           cnt16, rbase, gtot, bucket, 0);
        fused_all<<<N_GROUPS, 256, 0, stream>>>(x, w, erow, ecol, ev, support,
                                                cnt16, rbase, gtot, bucket, 1);
        fused_all<<<GEMM_FALLBACK_BASE + N_GROUPS, 256, 0, stream>>>(
            x, w, erow, ecol, ev, support, cnt16, rbase, gtot, bucket, 2);
    }

    reduce_group<<<N_GROUPS, 1024, 0, stream>>>(gtot, bucket, support, out);
}

// Round 8
// 131.821 us; speedup vs baseline: 3.3738x; 2.9204x over previous
//
#include <hip/hip_runtime.h>

#define N_NODES 50000
#define N_EDGES 800000
#define IN_DIM 128
#define OUT_DIM 64

#define GROUP_SHIFT 6                 // 64 rows per group
#define GROUP_ROWS 64
#define N_GROUPS 782                  // ceil(50000/64)
#define SLAB 1216                     // slab capacity per group (mean 1024, +6 sigma)
#define CHUNK2 8192                   // edges per fill block (was 2048)
#define FILL_BLOCKS 98                // 98*8192 = 802816 >= 800000; grid 880 = 1 round
#define GPAD 16                       // gcursor stride: one counter per 64B line

typedef _Float16 h2 __attribute__((ext_vector_type(2)));
typedef _Float16 h4 __attribute__((ext_vector_type(4)));
typedef _Float16 h8 __attribute__((ext_vector_type(8)));
typedef float    f4 __attribute__((ext_vector_type(4)));

#define LDK 136    // padded fp16 K-stride (multiple of 8 -> 16B-aligned b128 rows)

// ---------------------------------------------------------------------------
// D1 (fused): blocks [0,98) = fill role; blocks [98,880) = MFMA fp16 GEMM
// per 64-row group (byte-identical compute to the proven 124.3us version).
// Claim-economics fix vs R0: (1) 64B-padded per-group cursors (no same-line
// RMW serialization across groups), (2) 98 fat fill blocks -> 77K claims
// instead of 280K, (3) de-phased claim walk.  Grid 880 <= 1024 co-resident
// (4 blocks/CU by LDS) -> single scheduling round, fill fully overlaps gemm.
// ---------------------------------------------------------------------------
__global__ __launch_bounds__(256) void fused_gemm_fill(const float* __restrict__ x,
                                                       const float* __restrict__ w,
                                                       const int* __restrict__ erow,
                                                       const int* __restrict__ ecol,
                                                       const float* __restrict__ eval,
                                                       _Float16* __restrict__ support,
                                                       int* __restrict__ gcursor,
                                                       int2* __restrict__ bucket) {
    __shared__ char smem[GROUP_ROWS * LDK * 2 + OUT_DIM * LDK * 2];  // 34816 B
    const int tid = threadIdx.x;

    if (blockIdx.x >= FILL_BLOCKS) {
        // ---- GEMM role (blocks 98..879, group = blockIdx-98) ----
        _Float16* xb = (_Float16*)smem;                          // [64][LDK]
        _Float16* wt = (_Float16*)(smem + GROUP_ROWS * LDK * 2); // [64][LDK], wt[n][k]

        // conflict-free wt staging (register transpose, fp16-pair stores)
        {
            const int n_s = tid >> 2;         // 0..63
            const int kp0 = tid & 3;
            #pragma unroll
            for (int it = 0; it < 16; ++it) {
                int kp = kp0 + (it << 2);     // k-pair index 0..63
                int k  = kp << 1;
                h2 hv = { (_Float16)w[(size_t)k * OUT_DIM + n_s],
                          (_Float16)w[(size_t)(k + 1) * OUT_DIM + n_s] };
                *(h2*)&wt[n_s * LDK + k] = hv;
            }
        }
        const int rowbase = (blockIdx.x - FILL_BLOCKS) * GROUP_ROWS;
        for (int i = tid; i < GROUP_ROWS * (IN_DIM / 4); i += 256) {
            int r  = i >> 5;
            int kq = i & 31;
            int row = rowbase + r;
            float4 v = (row < N_NODES)
                           ? *(const float4*)&x[(size_t)row * IN_DIM + kq * 4]
                           : make_float4(0.f, 0.f, 0.f, 0.f);
            h4 hv = { (_Float16)v.x, (_Float16)v.y, (_Float16)v.z, (_Float16)v.w };
            *(h4*)&xb[r * LDK + kq * 4] = hv;
        }
        __syncthreads();

        const int wave = tid >> 6;
        const int lane = tid & 63;
        const int mrow = lane & 15;
        const int quad = lane >> 4;
        const int m0   = wave * 16;

        f4 acc[4];
        #pragma unroll
        for (int t = 0; t < 4; ++t) acc[t] = (f4){0.f, 0.f, 0.f, 0.f};

        #pragma unroll
        for (int ks = 0; ks < 4; ++ks) {
            int kof = ks * 32 + quad * 8;
            h8 a = *(h8*)&xb[(m0 + mrow) * LDK + kof];
            #pragma unroll
            for (int t = 0; t < 4; ++t) {
                h8 b = *(h8*)&wt[(t * 16 + mrow) * LDK + kof];
                acc[t] = __builtin_amdgcn_mfma_f32_16x16x32_f16(a, b, acc[t], 0, 0, 0);
            }
        }

        #pragma unroll
        for (int t = 0; t < 4; ++t) {
            #pragma unroll
            for (int r = 0; r < 4; ++r) {
                int row = rowbase + m0 + quad * 4 + r;
                if (row < N_NODES)
                    support[(size_t)row * OUT_DIM + t * 16 + mrow] = (_Float16)acc[t][r];
            }
        }
    } else {
        // ---- fill role (blocks 0..97) ----
        int* lcnt  = (int*)smem;
        int* lbase = lcnt + N_GROUPS;
        for (int i = tid; i < N_GROUPS; i += 256) lcnt[i] = 0;
        __syncthreads();
        const int base = blockIdx.x * CHUNK2;
        #pragma unroll 4
        for (int i = 0; i < CHUNK2 / 256; ++i) {
            int e = base + tid + i * 256;
            if (e < N_EDGES) atomicAdd(&lcnt[erow[e] >> GROUP_SHIFT], 1);
        }
        __syncthreads();
        // de-phased claim walk: rotate start per block so per-line RMW
        // arrivals at L2 are spread instead of all blocks queuing on line 0
        const int off = (blockIdx.x * 131) % N_GROUPS;
        for (int ii = tid; ii < N_GROUPS; ii += 256) {
            int i = ii + off;
            if (i >= N_GROUPS) i -= N_GROUPS;
            int c = lcnt[i];
            lbase[i] = c ? atomicAdd(&gcursor[i * GPAD], c) : 0;
            lcnt[i]  = 0;
        }
        __syncthreads();
        #pragma unroll 4
        for (int i = 0; i < CHUNK2 / 256; ++i) {
            int e = base + tid + i * 256;
            if (e < N_EDGES) {
                int r = erow[e];
                int g = r >> GROUP_SHIFT;
                int p = atomicAdd(&lcnt[g], 1);
                bucket[(size_t)g * SLAB + lbase[g] + p] =
                    make_int2(((r & (GROUP_ROWS - 1)) << 16) | ecol[e],
                              __float_as_int(eval[e]));
            }
        }
    }
}

// ---------------------------------------------------------------------------
// D2 (proven R0 code): one 1024-thread block per 64-row group.  Slab staged
// to LDS once; histogram + wave-0 scan + in-LDS counting sort; one
// (row, colgroup) per thread; gather loop unrolled x2 with dual
// accumulators; fused ReLU.
// ---------------------------------------------------------------------------
__global__ __launch_bounds__(1024) void reduce_group(const int* __restrict__ gcursor,
                                                     const int2* __restrict__ bucket,
                                                     const _Float16* __restrict__ support,
                                                     float* __restrict__ out) {
    __shared__ int2 ebuf[SLAB];
    __shared__ int2 ebuf2[SLAB];
    __shared__ int  rcnt[GROUP_ROWS];
    __shared__ int  rstart[GROUP_ROWS + 1];
    __shared__ int  rcur[GROUP_ROWS];
    const int grp = blockIdx.x;
    const int cnt = min(gcursor[grp * GPAD], SLAB);
    const size_t sb = (size_t)grp * SLAB;
    const int tid = threadIdx.x;

    if (tid < GROUP_ROWS) rcnt[tid] = 0;
    __syncthreads();
    for (int j = tid; j < cnt; j += 1024) {
        int2 cv = bucket[sb + j];
        ebuf[j] = cv;
        atomicAdd(&rcnt[cv.x >> 16], 1);
    }
    __syncthreads();
    if (tid < GROUP_ROWS) {
        int v = rcnt[tid];
        int s = v;
        #pragma unroll
        for (int off = 1; off < 64; off <<= 1) {
            int t = __shfl_up(s, off, 64);
            if (tid >= off) s += t;
        }
        rstart[tid] = s - v;
        rcur[tid]   = s - v;
        if (tid == 63) rstart[64] = s;
    }
    __syncthreads();
    for (int j = tid; j < cnt; j += 1024) {
        int2 cv = ebuf[j];
        int rl = cv.x >> 16;
        int p  = atomicAdd(&rcur[rl], 1);
        ebuf2[p] = cv;
    }
    __syncthreads();

    const int g  = tid & 15;
    const int lr = tid >> 4;
    const int row = grp * GROUP_ROWS + lr;
    const int jb = rstart[lr];
    const int je = rstart[lr + 1];
    float4 acc0 = make_float4(0.f, 0.f, 0.f, 0.f);
    float4 acc1 = make_float4(0.f, 0.f, 0.f, 0.f);
    int j = jb;
    for (; j + 1 < je; j += 2) {
        int2 cv0 = ebuf2[j];
        int2 cv1 = ebuf2[j + 1];
        float v0 = __int_as_float(cv0.y);
        float v1 = __int_as_float(cv1.y);
        h4 s0 = *(const h4*)&support[(size_t)(cv0.x & 0xFFFF) * OUT_DIM + g * 4];
        h4 s1 = *(const h4*)&support[(size_t)(cv1.x & 0xFFFF) * OUT_DIM + g * 4];
        acc0.x += v0 * (float)s0[0];
        acc0.y += v0 * (float)s0[1];
        acc0.z += v0 * (float)s0[2];
        acc0.w += v0 * (float)s0[3];
        acc1.x += v1 * (float)s1[0];
        acc1.y += v1 * (float)s1[1];
        acc1.z += v1 * (float)s1[2];
        acc1.w += v1 * (float)s1[3];
    }
    if (j < je) {
        int2 cv = ebuf2[j];
        float v = __int_as_float(cv.y);
        h4 sr = *(const h4*)&support[(size_t)(cv.x & 0xFFFF) * OUT_DIM + g * 4];
        acc0.x += v * (float)sr[0];
        acc0.y += v * (float)sr[1];
        acc0.z += v * (float)sr[2];
        acc0.w += v * (float)sr[3];
    }
    if (row < N_NODES) {
        float4 a;
        a.x = fmaxf(acc0.x + acc1.x, 0.f);
        a.y = fmaxf(acc0.y + acc1.y, 0.f);
        a.z = fmaxf(acc0.z + acc1.z, 0.f);
        a.w = fmaxf(acc0.w + acc1.w, 0.f);
        *(float4*)&out[(size_t)row * OUT_DIM + g * 4] = a;
    }
}

extern "C" void kernel_launch(void* const* d_in, const int* in_sizes, int n_in,
                              void* d_out, int out_size, void* d_ws, size_t ws_size,
                              hipStream_t stream) {
    const float* x    = (const float*)d_in[0];
    const int*   erow = (const int*)  d_in[1];
    const int*   ecol = (const int*)  d_in[2];
    const float* ev   = (const float*)d_in[3];
    const float* w    = (const float*)d_in[4];
    float* out = (float*)d_out;

    // workspace layout (16B-aligned), total ~14.1 MB
    char* ws = (char*)d_ws;
    _Float16* support = (_Float16*)ws;               //  6,400,000 B
    int*  gcursor = (int*)(ws + 6400000);            //     50,048 B (782 * 64B lines)
    int2* bucket  = (int2*)(ws + 6450048);           //  7,607,296 B

    hipMemsetAsync(gcursor, 0, sizeof(int) * N_GROUPS * GPAD, stream);

    fused_gemm_fill<<<FILL_BLOCKS + N_GROUPS, 256, 0, stream>>>(
        x, w, erow, ecol, ev, support, gcursor, bucket);

    reduce_group<<<N_GROUPS, 1024, 0, stream>>>(gcursor, bucket, support, out);
}